// Round 1
// baseline (828.905 us; speedup 1.0000x reference)
//
#include <hip/hip_runtime.h>

#define LEAKY 0.2f

__device__ __forceinline__ float wave_reduce_add64(float v) {
  #pragma unroll
  for (int m = 1; m < 64; m <<= 1) v += __shfl_xor(v, m, 64);
  return v;
}

// ---------------- GEMM + attention dots ----------------
// h[n,c] = dot(x[n,:], W[c,:]);  sa[n,hd] = sum_c h*att_s;  da likewise.
// lane = channel (CO channels); W row lives in VGPRs; nodes iterated per wave.
template<int K, int CO, int H>
__global__ __launch_bounds__(256)
void gat_gemm(const float* __restrict__ x, const float* __restrict__ W,
              const float* __restrict__ atts, const float* __restrict__ attd,
              float* __restrict__ h, float* __restrict__ sa, float* __restrict__ da,
              int N) {
  constexpr int NPW = 64 / CO;   // nodes per wave
  constexpr int C = CO / H;      // channels per head (always 32 here)
  const int lane = (int)(threadIdx.x & 63);
  int wave = (int)((blockIdx.x * blockDim.x + threadIdx.x) >> 6);
  wave = __builtin_amdgcn_readfirstlane(wave);
  const int nwaves = (int)((gridDim.x * blockDim.x) >> 6);
  const int c = lane % CO;
  const int sub = lane / CO;
  const int head = c / C;
  const int ci = c % C;

  float wreg[K];
  #pragma unroll
  for (int k = 0; k < K; k += 4) {
    float4 wv = *(const float4*)(W + (size_t)c * K + k);
    wreg[k] = wv.x; wreg[k + 1] = wv.y; wreg[k + 2] = wv.z; wreg[k + 3] = wv.w;
  }
  const float as_c = atts[head * C + ci];
  const float ad_c = attd[head * C + ci];

  for (int base = wave * NPW; base < N; base += nwaves * NPW) {
    const int n = base + sub;
    const int nc = n < N ? n : N - 1;
    const float* __restrict__ xr = x + (size_t)nc * K;
    float acc = 0.f;
    #pragma unroll
    for (int k = 0; k < K; k += 4) {
      float4 xv = *(const float4*)(xr + k);
      acc = fmaf(xv.x, wreg[k],     acc);
      acc = fmaf(xv.y, wreg[k + 1], acc);
      acc = fmaf(xv.z, wreg[k + 2], acc);
      acc = fmaf(xv.w, wreg[k + 3], acc);
    }
    float ps = acc * as_c;
    float pd = acc * ad_c;
    #pragma unroll
    for (int m = 1; m < C; m <<= 1) {   // reduce within 32-lane head group
      ps += __shfl_xor(ps, m, 64);
      pd += __shfl_xor(pd, m, 64);
    }
    if (n < N) {
      h[(size_t)n * CO + c] = acc;
      if (ci == 0) {
        sa[n * H + head] = ps;
        da[n * H + head] = pd;
      }
    }
  }
}

// ---------------- Edge aggregation (CSR by dst), softmax w/o max-shift ----------------
// One wave handles NPW dst nodes; lane = (sub, head, channel). Optional fused LN+ReLU.
template<int H, int C, bool LN>
__global__ __launch_bounds__(256)
void gat_edge(const float* __restrict__ h, const float* __restrict__ sa,
              const float* __restrict__ da, const int* __restrict__ rowp,
              const int* __restrict__ col, const float* __restrict__ bias,
              const float* __restrict__ gamma, const float* __restrict__ beta,
              float* __restrict__ out, int N) {
  constexpr int HC = H * C;
  constexpr int NPW = 64 / HC;
  static_assert(!LN || NPW == 1, "LN needs full wave per node");
  const int lane = (int)(threadIdx.x & 63);
  const int wave = (int)((blockIdx.x * blockDim.x + threadIdx.x) >> 6);
  const int sub = lane / HC;
  const int cc = lane % HC;
  const int head = cc / C;
  const int n = wave * NPW + sub;
  const bool valid = (n < N);
  const int nc = valid ? n : 0;
  const int beg = rowp[nc];
  const int end = rowp[nc + 1];
  const float dv = da[nc * H + head];
  float acc = 0.f, wsum = 0.f;
  for (int i = beg; i < end; ++i) {
    const int s = col[i];
    float lg = sa[s * H + head] + dv;
    lg = lg >= 0.f ? lg : LEAKY * lg;
    const float w = __expf(lg);
    wsum += w;
    acc = fmaf(w, h[(size_t)s * HC + cc], acc);
  }
  float v = acc / fmaxf(wsum, 1e-16f) + h[(size_t)nc * HC + cc] + bias[cc];
  if constexpr (LN) {
    const float mu = wave_reduce_add64(v) * (1.f / 64.f);
    const float d = v - mu;
    const float var = wave_reduce_add64(d * d) * (1.f / 64.f);
    float y = d * rsqrtf(var + 1e-5f) * gamma[cc] + beta[cc];
    v = fmaxf(y, 0.f);
  }
  if (valid) out[(size_t)n * HC + cc] = v;
}

// ---------------- CSR build ----------------
__global__ void k_hist(const int* __restrict__ dst, int* __restrict__ deg, int E) {
  int e = blockIdx.x * blockDim.x + threadIdx.x;
  if (e < E) atomicAdd(&deg[dst[e]], 1);
}

__global__ void k_blocksum(const int* __restrict__ deg, int* __restrict__ bsum, int N) {
  __shared__ int sm[256];
  const int t = threadIdx.x;
  const int base = blockIdx.x * 1024 + t * 4;
  int s = 0;
  #pragma unroll
  for (int j = 0; j < 4; ++j) { int i = base + j; if (i < N) s += deg[i]; }
  sm[t] = s; __syncthreads();
  #pragma unroll
  for (int off = 128; off > 0; off >>= 1) {
    if (t < off) sm[t] += sm[t + off];
    __syncthreads();
  }
  if (t == 0) bsum[blockIdx.x] = sm[0];
}

__global__ void k_scan_bsum(int* __restrict__ bsum, int nb, int* __restrict__ rowp_last) {
  if (threadIdx.x == 0 && blockIdx.x == 0) {
    int run = 0;
    for (int i = 0; i < nb; ++i) { int v = bsum[i]; bsum[i] = run; run += v; }
    *rowp_last = run;
  }
}

__global__ void k_scan_final(const int* __restrict__ deg, const int* __restrict__ bsum,
                             int* __restrict__ rowp, int* __restrict__ cursor, int N) {
  __shared__ int sm[256];
  const int t = threadIdx.x;
  const int base = blockIdx.x * 1024 + t * 4;
  int v[4];
  #pragma unroll
  for (int j = 0; j < 4; ++j) { int i = base + j; v[j] = (i < N) ? deg[i] : 0; }
  const int tot = v[0] + v[1] + v[2] + v[3];
  sm[t] = tot; __syncthreads();
  #pragma unroll
  for (int off = 1; off < 256; off <<= 1) {
    int xv = (t >= off) ? sm[t - off] : 0;
    __syncthreads();
    sm[t] += xv;
    __syncthreads();
  }
  int excl = sm[t] - tot + bsum[blockIdx.x];
  #pragma unroll
  for (int j = 0; j < 4; ++j) {
    int i = base + j;
    if (i < N) { rowp[i] = excl; cursor[i] = excl; excl += v[j]; }
  }
}

__global__ void k_scatter(const int* __restrict__ src, const int* __restrict__ dst,
                          int* __restrict__ cursor, int* __restrict__ col, int E) {
  int e = blockIdx.x * blockDim.x + threadIdx.x;
  if (e < E) {
    int p = atomicAdd(&cursor[dst[e]], 1);
    col[p] = src[e];
  }
}

extern "C" void kernel_launch(void* const* d_in, const int* in_sizes, int n_in,
                              void* d_out, int out_size, void* d_ws, size_t ws_size,
                              hipStream_t stream) {
  const float* x   = (const float*)d_in[0];
  const int* esrc  = (const int*)d_in[1];
  const int* edst  = (const int*)d_in[2];
  const float* W1  = (const float*)d_in[3];
  const float* as1 = (const float*)d_in[4];
  const float* ad1 = (const float*)d_in[5];
  const float* b1  = (const float*)d_in[6];
  const float* W2  = (const float*)d_in[7];
  const float* as2 = (const float*)d_in[8];
  const float* ad2 = (const float*)d_in[9];
  const float* b2  = (const float*)d_in[10];
  const float* W3  = (const float*)d_in[11];
  const float* as3 = (const float*)d_in[12];
  const float* ad3 = (const float*)d_in[13];
  const float* b3  = (const float*)d_in[14];
  const float* g1  = (const float*)d_in[15];
  const float* be1 = (const float*)d_in[16];
  const float* g2  = (const float*)d_in[17];
  const float* be2 = (const float*)d_in[18];

  const int N = in_sizes[0] / 128;
  const int E = in_sizes[1];

  char* ws = (char*)d_ws;
  size_t off = 0;
  auto alloc = [&](size_t bytes) -> void* {
    void* p = ws + off;
    off = (off + bytes + 255) & ~(size_t)255;
    return p;
  };
  float* hbuf  = (float*)alloc((size_t)N * 64 * 4);
  float* lnbuf = (float*)alloc((size_t)N * 64 * 4);
  float* sab   = (float*)alloc((size_t)N * 2 * 4);
  float* dab   = (float*)alloc((size_t)N * 2 * 4);
  int* deg     = (int*)alloc((size_t)N * 4);
  int* rowp    = (int*)alloc((size_t)(N + 1) * 4);
  int* cursor  = (int*)alloc((size_t)N * 4);
  int* colb    = (int*)alloc((size_t)E * 4);
  int* bsum    = (int*)alloc(4096);
  (void)ws_size; (void)n_in; (void)out_size;

  // ---- CSR build (once per call; shared by all 3 layers) ----
  hipMemsetAsync(deg, 0, (size_t)N * 4, stream);
  const int gE = (E + 255) / 256;
  k_hist<<<gE, 256, 0, stream>>>(edst, deg, E);
  const int nb = (N + 1023) / 1024;
  k_blocksum<<<nb, 256, 0, stream>>>(deg, bsum, N);
  k_scan_bsum<<<1, 64, 0, stream>>>(bsum, nb, rowp + N);
  k_scan_final<<<nb, 256, 0, stream>>>(deg, bsum, rowp, cursor, N);
  k_scatter<<<gE, 256, 0, stream>>>(esrc, edst, cursor, colb, E);

  const int GB = 1024;                 // gemm grid (grid-stride over nodes)
  const int gEdge  = (N + 3) / 4;      // NPW=1: 4 nodes per 256-thread block
  const int gEdge3 = (N + 7) / 8;      // NPW=2: 8 nodes per block

  // ---- Layer 1: 128 -> (2 heads x 32) + LN + ReLU ----
  gat_gemm<128, 64, 2><<<GB, 256, 0, stream>>>(x, W1, as1, ad1, hbuf, sab, dab, N);
  gat_edge<2, 32, true><<<gEdge, 256, 0, stream>>>(hbuf, sab, dab, rowp, colb, b1, g1, be1, lnbuf, N);

  // ---- Layer 2: 64 -> (2 heads x 32) + LN + ReLU ----
  gat_gemm<64, 64, 2><<<GB, 256, 0, stream>>>(lnbuf, W2, as2, ad2, hbuf, sab, dab, N);
  gat_edge<2, 32, true><<<gEdge, 256, 0, stream>>>(hbuf, sab, dab, rowp, colb, b2, g2, be2, lnbuf, N);

  // ---- Layer 3: 64 -> (1 head x 32), no LN ----
  gat_gemm<64, 32, 1><<<GB, 256, 0, stream>>>(lnbuf, W3, as3, ad3, hbuf, sab, dab, N);
  gat_edge<1, 32, false><<<gEdge3, 256, 0, stream>>>(hbuf, sab, dab, rowp, colb, b3, nullptr, nullptr,
                                                     (float*)d_out, N);
}

// Round 2
// 512.943 us; speedup vs baseline: 1.6160x; 1.6160x over previous
//
#include <hip/hip_runtime.h>

#define LEAKY 0.2f

__device__ __forceinline__ float wave_reduce_add64(float v) {
  #pragma unroll
  for (int m = 1; m < 64; m <<= 1) v += __shfl_xor(v, m, 64);
  return v;
}

// ---------------- Tiled GEMM + fused attention dots ----------------
// h[n,c] = dot(x[n,:], W[c,:]); sa/da fused via cross-lane reduce.
// Thread tile: 4 nodes x 4 channels (channels strided by CG for bank-friendly LDS reads).
template<int K, int CO, int H>
__global__ __launch_bounds__(256)
void gat_gemm2(const float* __restrict__ x, const float* __restrict__ W,
               const float* __restrict__ atts, const float* __restrict__ attd,
               float* __restrict__ h, float* __restrict__ sa, float* __restrict__ da,
               int N) {
  constexpr int CG = CO / 4;          // channel groups: 16 (CO=64) or 8 (CO=32)
  constexpr int BM = (256 / CG) * 4;  // nodes per block: 64 or 128
  constexpr int BK = 64;
  constexpr int NK = K / BK;
  constexpr int C = CO / H;

  __shared__ float xs[BM][BK + 4];
  __shared__ float ws[CO][K + 4];

  const int t = (int)threadIdx.x;
  const int cg = t % CG;
  const int ng = t / CG;              // node group within block
  const int n0 = (int)blockIdx.x * BM;

  // stage full W (small: <= 33 KB)
  constexpr int WF4 = CO * K / 4;
  for (int f = t; f < WF4; f += 256) {
    const int r = f / (K / 4), c4 = f % (K / 4);
    *(float4*)&ws[r][c4 * 4] = *(const float4*)(W + (size_t)r * K + c4 * 4);
  }

  float acc[4][4] = {};  // [node i][channel j], channel c = cg + CG*j

  for (int kb = 0; kb < NK; ++kb) {
    __syncthreads();  // protect xs from previous iteration readers (and orders W stage)
    constexpr int XF4 = BM * BK / 4;
    for (int f = t; f < XF4; f += 256) {
      const int r = f / (BK / 4), c4 = f % (BK / 4);
      int row = n0 + r; row = row < N ? row : N - 1;
      *(float4*)&xs[r][c4 * 4] = *(const float4*)(x + (size_t)row * K + kb * BK + c4 * 4);
    }
    __syncthreads();
    #pragma unroll
    for (int k = 0; k < BK; k += 4) {
      float4 xa[4], wb[4];
      #pragma unroll
      for (int i = 0; i < 4; ++i) xa[i] = *(const float4*)&xs[ng * 4 + i][k];
      #pragma unroll
      for (int j = 0; j < 4; ++j) wb[j] = *(const float4*)&ws[cg + CG * j][kb * BK + k];
      #pragma unroll
      for (int i = 0; i < 4; ++i) {
        #pragma unroll
        for (int j = 0; j < 4; ++j) {
          acc[i][j] = fmaf(xa[i].x, wb[j].x, acc[i][j]);
          acc[i][j] = fmaf(xa[i].y, wb[j].y, acc[i][j]);
          acc[i][j] = fmaf(xa[i].z, wb[j].z, acc[i][j]);
          acc[i][j] = fmaf(xa[i].w, wb[j].w, acc[i][j]);
        }
      }
    }
  }

  // fused sa/da: partial per thread, reduce across the CG lanes of each node group
  float as_[4], ad_[4];
  #pragma unroll
  for (int j = 0; j < 4; ++j) {
    as_[j] = atts[cg + CG * j];
    ad_[j] = attd[cg + CG * j];
  }
  float ps[4][H] = {}, pd[4][H] = {};
  #pragma unroll
  for (int i = 0; i < 4; ++i) {
    #pragma unroll
    for (int j = 0; j < 4; ++j) {
      constexpr int dummy = 0; (void)dummy;
      const int hd = (CG * j) / C;  // head of channel cg+CG*j (cg < CG <= C)
      ps[i][hd] = fmaf(acc[i][j], as_[j], ps[i][hd]);
      pd[i][hd] = fmaf(acc[i][j], ad_[j], pd[i][hd]);
    }
  }
  #pragma unroll
  for (int m = 1; m < CG; m <<= 1) {
    #pragma unroll
    for (int i = 0; i < 4; ++i) {
      #pragma unroll
      for (int hd = 0; hd < H; ++hd) {
        ps[i][hd] += __shfl_xor(ps[i][hd], m, 64);
        pd[i][hd] += __shfl_xor(pd[i][hd], m, 64);
      }
    }
  }

  #pragma unroll
  for (int i = 0; i < 4; ++i) {
    const int n = n0 + ng * 4 + i;
    if (n < N) {
      #pragma unroll
      for (int j = 0; j < 4; ++j) h[(size_t)n * CO + cg + CG * j] = acc[i][j];
      if (cg == 0) {
        #pragma unroll
        for (int hd = 0; hd < H; ++hd) {
          sa[n * H + hd] = ps[i][hd];
          da[n * H + hd] = pd[i][hd];
        }
      }
    }
  }
}

// ---------------- Edge aggregation (CSR by dst), 4x unrolled for ILP ----------------
template<int H, int C, bool LN>
__global__ __launch_bounds__(256)
void gat_edge(const float* __restrict__ h, const float* __restrict__ sa,
              const float* __restrict__ da, const int* __restrict__ rowp,
              const int* __restrict__ col, const float* __restrict__ bias,
              const float* __restrict__ gamma, const float* __restrict__ beta,
              float* __restrict__ out, int N) {
  constexpr int HC = H * C;
  constexpr int NPW = 64 / HC;
  static_assert(!LN || NPW == 1, "LN needs full wave per node");
  const int lane = (int)(threadIdx.x & 63);
  const int wave = (int)((blockIdx.x * blockDim.x + threadIdx.x) >> 6);
  const int sub = lane / HC;
  const int cc = lane % HC;
  const int head = cc / C;
  const int n = wave * NPW + sub;
  const bool valid = (n < N);
  const int nc = valid ? n : 0;
  const int beg = rowp[nc];
  const int end = rowp[nc + 1];
  const float dv = da[nc * H + head];

  float acc0 = 0.f, acc1 = 0.f, acc2 = 0.f, acc3 = 0.f;
  float ws0 = 0.f, ws1 = 0.f, ws2 = 0.f, ws3 = 0.f;
  int i = beg;
  for (; i + 4 <= end; i += 4) {
    const int s0 = col[i], s1 = col[i + 1], s2 = col[i + 2], s3 = col[i + 3];
    float l0 = sa[s0 * H + head] + dv;
    float l1 = sa[s1 * H + head] + dv;
    float l2 = sa[s2 * H + head] + dv;
    float l3 = sa[s3 * H + head] + dv;
    const float h0 = h[(size_t)s0 * HC + cc];
    const float h1 = h[(size_t)s1 * HC + cc];
    const float h2 = h[(size_t)s2 * HC + cc];
    const float h3 = h[(size_t)s3 * HC + cc];
    l0 = l0 >= 0.f ? l0 : LEAKY * l0;
    l1 = l1 >= 0.f ? l1 : LEAKY * l1;
    l2 = l2 >= 0.f ? l2 : LEAKY * l2;
    l3 = l3 >= 0.f ? l3 : LEAKY * l3;
    const float w0 = __expf(l0), w1 = __expf(l1), w2 = __expf(l2), w3 = __expf(l3);
    ws0 += w0; ws1 += w1; ws2 += w2; ws3 += w3;
    acc0 = fmaf(w0, h0, acc0);
    acc1 = fmaf(w1, h1, acc1);
    acc2 = fmaf(w2, h2, acc2);
    acc3 = fmaf(w3, h3, acc3);
  }
  for (; i < end; ++i) {
    const int s = col[i];
    float lg = sa[s * H + head] + dv;
    lg = lg >= 0.f ? lg : LEAKY * lg;
    const float w = __expf(lg);
    ws0 += w;
    acc0 = fmaf(w, h[(size_t)s * HC + cc], acc0);
  }
  const float wsum = (ws0 + ws1) + (ws2 + ws3);
  const float acc = (acc0 + acc1) + (acc2 + acc3);

  float v = acc / fmaxf(wsum, 1e-16f) + h[(size_t)nc * HC + cc] + bias[cc];
  if constexpr (LN) {
    const float mu = wave_reduce_add64(v) * (1.f / 64.f);
    const float d = v - mu;
    const float var = wave_reduce_add64(d * d) * (1.f / 64.f);
    float y = d * rsqrtf(var + 1e-5f) * gamma[cc] + beta[cc];
    v = fmaxf(y, 0.f);
  }
  if (valid) out[(size_t)n * HC + cc] = v;
}

// ---------------- CSR build ----------------
__global__ void k_hist(const int* __restrict__ dst, int* __restrict__ deg, int E) {
  int e = blockIdx.x * blockDim.x + threadIdx.x;
  if (e < E) atomicAdd(&deg[dst[e]], 1);
}

__global__ void k_blocksum(const int* __restrict__ deg, int* __restrict__ bsum, int N) {
  __shared__ int sm[256];
  const int t = threadIdx.x;
  const int base = blockIdx.x * 1024 + t * 4;
  int s = 0;
  #pragma unroll
  for (int j = 0; j < 4; ++j) { int i = base + j; if (i < N) s += deg[i]; }
  sm[t] = s; __syncthreads();
  #pragma unroll
  for (int off = 128; off > 0; off >>= 1) {
    if (t < off) sm[t] += sm[t + off];
    __syncthreads();
  }
  if (t == 0) bsum[blockIdx.x] = sm[0];
}

__global__ void k_scan_bsum(int* __restrict__ bsum, int nb, int* __restrict__ rowp_last) {
  if (threadIdx.x == 0 && blockIdx.x == 0) {
    int run = 0;
    for (int i = 0; i < nb; ++i) { int v = bsum[i]; bsum[i] = run; run += v; }
    *rowp_last = run;
  }
}

__global__ void k_scan_final(const int* __restrict__ deg, const int* __restrict__ bsum,
                             int* __restrict__ rowp, int* __restrict__ cursor, int N) {
  __shared__ int sm[256];
  const int t = threadIdx.x;
  const int base = blockIdx.x * 1024 + t * 4;
  int v[4];
  #pragma unroll
  for (int j = 0; j < 4; ++j) { int i = base + j; v[j] = (i < N) ? deg[i] : 0; }
  const int tot = v[0] + v[1] + v[2] + v[3];
  sm[t] = tot; __syncthreads();
  #pragma unroll
  for (int off = 1; off < 256; off <<= 1) {
    int xv = (t >= off) ? sm[t - off] : 0;
    __syncthreads();
    sm[t] += xv;
    __syncthreads();
  }
  int excl = sm[t] - tot + bsum[blockIdx.x];
  #pragma unroll
  for (int j = 0; j < 4; ++j) {
    int i = base + j;
    if (i < N) { rowp[i] = excl; cursor[i] = excl; excl += v[j]; }
  }
}

__global__ void k_scatter(const int* __restrict__ src, const int* __restrict__ dst,
                          int* __restrict__ cursor, int* __restrict__ col, int E) {
  int e = blockIdx.x * blockDim.x + threadIdx.x;
  if (e < E) {
    int p = atomicAdd(&cursor[dst[e]], 1);
    col[p] = src[e];
  }
}

extern "C" void kernel_launch(void* const* d_in, const int* in_sizes, int n_in,
                              void* d_out, int out_size, void* d_ws, size_t ws_size,
                              hipStream_t stream) {
  const float* x   = (const float*)d_in[0];
  const int* esrc  = (const int*)d_in[1];
  const int* edst  = (const int*)d_in[2];
  const float* W1  = (const float*)d_in[3];
  const float* as1 = (const float*)d_in[4];
  const float* ad1 = (const float*)d_in[5];
  const float* b1  = (const float*)d_in[6];
  const float* W2  = (const float*)d_in[7];
  const float* as2 = (const float*)d_in[8];
  const float* ad2 = (const float*)d_in[9];
  const float* b2  = (const float*)d_in[10];
  const float* W3  = (const float*)d_in[11];
  const float* as3 = (const float*)d_in[12];
  const float* ad3 = (const float*)d_in[13];
  const float* b3  = (const float*)d_in[14];
  const float* g1  = (const float*)d_in[15];
  const float* be1 = (const float*)d_in[16];
  const float* g2  = (const float*)d_in[17];
  const float* be2 = (const float*)d_in[18];

  const int N = in_sizes[0] / 128;
  const int E = in_sizes[1];

  char* ws = (char*)d_ws;
  size_t off = 0;
  auto alloc = [&](size_t bytes) -> void* {
    void* p = ws + off;
    off = (off + bytes + 255) & ~(size_t)255;
    return p;
  };
  float* hbuf  = (float*)alloc((size_t)N * 64 * 4);
  float* lnbuf = (float*)alloc((size_t)N * 64 * 4);
  float* sab   = (float*)alloc((size_t)N * 2 * 4);
  float* dab   = (float*)alloc((size_t)N * 2 * 4);
  int* deg     = (int*)alloc((size_t)N * 4);
  int* rowp    = (int*)alloc((size_t)(N + 1) * 4);
  int* cursor  = (int*)alloc((size_t)N * 4);
  int* colb    = (int*)alloc((size_t)E * 4);
  int* bsum    = (int*)alloc(4096);
  (void)ws_size; (void)n_in; (void)out_size;

  // ---- CSR build (shared by all 3 layers) ----
  hipMemsetAsync(deg, 0, (size_t)N * 4, stream);
  const int gE = (E + 255) / 256;
  k_hist<<<gE, 256, 0, stream>>>(edst, deg, E);
  const int nb = (N + 1023) / 1024;
  k_blocksum<<<nb, 256, 0, stream>>>(deg, bsum, N);
  k_scan_bsum<<<1, 64, 0, stream>>>(bsum, nb, rowp + N);
  k_scan_final<<<nb, 256, 0, stream>>>(deg, bsum, rowp, cursor, N);
  k_scatter<<<gE, 256, 0, stream>>>(esrc, edst, cursor, colb, E);

  const int gG12 = (N + 63) / 64;      // BM=64
  const int gG3  = (N + 127) / 128;    // BM=128
  const int gEdge  = (N + 3) / 4;      // NPW=1: 4 nodes / 256-thread block
  const int gEdge3 = (N + 7) / 8;      // NPW=2

  // ---- Layer 1: 128 -> (2x32) + LN + ReLU ----
  gat_gemm2<128, 64, 2><<<gG12, 256, 0, stream>>>(x, W1, as1, ad1, hbuf, sab, dab, N);
  gat_edge<2, 32, true><<<gEdge, 256, 0, stream>>>(hbuf, sab, dab, rowp, colb, b1, g1, be1, lnbuf, N);

  // ---- Layer 2: 64 -> (2x32) + LN + ReLU ----
  gat_gemm2<64, 64, 2><<<gG12, 256, 0, stream>>>(lnbuf, W2, as2, ad2, hbuf, sab, dab, N);
  gat_edge<2, 32, true><<<gEdge, 256, 0, stream>>>(hbuf, sab, dab, rowp, colb, b2, g2, be2, lnbuf, N);

  // ---- Layer 3: 64 -> (1x32), no LN ----
  gat_gemm2<64, 32, 1><<<gG3, 256, 0, stream>>>(lnbuf, W3, as3, ad3, hbuf, sab, dab, N);
  gat_edge<1, 32, false><<<gEdge3, 256, 0, stream>>>(hbuf, sab, dab, rowp, colb, b3, nullptr, nullptr,
                                                     (float*)d_out, N);
}